// Round 4
// baseline (69.607 us; speedup 1.0000x reference)
//
#include <hip/hip_runtime.h>
#include <math.h>

// Problem constants (match reference)
#define VOCAB   100000
#define EMBED_D 128
#define BATCH_N 16384
#define CTX     8
#define NNEG    5

#define NBLOCKS 1024
#define TPB     256                     // 4 waves/block
#define WPB     (TPB / 64)
#define NWAVES  (NBLOCKS * WPB)         // 4096 waves
#define EPW     (BATCH_N / NWAVES)      // 4 elements per wave (blocked)

// Fused kernel: stage-1 gather/partials (identical body to round 3) + last-block
// final reduction & log-sigmoid epilogue via ticket-counter. Counter is zeroed
// each call by a hipMemsetAsync node, so behavior is call-invariant.
__global__ __launch_bounds__(TPB) void cbow_fused_kernel(
    const int* __restrict__ pos_u,   // [B, C]
    const int* __restrict__ pos_w,   // [B]
    const int* __restrict__ neg_w,   // [B, NEG]
    const float* __restrict__ W,     // [VOCAB, D]
    float* __restrict__ partials,    // [6][NBLOCKS] in d_ws
    unsigned int* __restrict__ counter, // 1 uint in d_ws (memset to 0 per call)
    float* __restrict__ out)
{
    const int lane = threadIdx.x & 63;
    const int wib  = threadIdx.x >> 6;
    const int g    = blockIdx.x * WPB + wib;

    const float2* __restrict__ W2 = (const float2*)W;   // 64 float2 per row

    float accs[6] = {0.f, 0.f, 0.f, 0.f, 0.f, 0.f};

    const int base = __builtin_amdgcn_readfirstlane(g * EPW);

    #pragma unroll
    for (int p = 0; p < EPW / 2; ++p) {
        const int e0 = base + 2 * p;
        const int e1 = e0 + 1;

        // ---- wave-uniform index loads (contiguous -> wide s_loads) ----
        int c0[CTX], c1[CTX];
        #pragma unroll
        for (int c = 0; c < CTX; ++c) {
            c0[c] = pos_u[e0 * CTX + c];
            c1[c] = pos_u[e1 * CTX + c];
        }
        const int ip0 = pos_w[e0];
        const int ip1 = pos_w[e1];
        int n0[NNEG], n1[NNEG];
        #pragma unroll
        for (int n = 0; n < NNEG; ++n) {
            n0[n] = neg_w[e0 * NNEG + n];
            n1[n] = neg_w[e1 * NNEG + n];
        }

        // ---- context-sum gathers for both elements (16 independent loads) ----
        float2 us0 = make_float2(0.f, 0.f);
        float2 us1 = make_float2(0.f, 0.f);
        #pragma unroll
        for (int c = 0; c < CTX; ++c) {
            const float2 a = W2[(size_t)c0[c] * (EMBED_D / 2) + lane];
            const float2 b = W2[(size_t)c1[c] * (EMBED_D / 2) + lane];
            us0.x += a.x; us0.y += a.y;
            us1.x += b.x; us1.y += b.y;
        }

        // ---- 12 target-row gathers + dot partials ----
        {
            const float2 a = W2[(size_t)ip0 * (EMBED_D / 2) + lane];
            const float2 b = W2[(size_t)ip1 * (EMBED_D / 2) + lane];
            accs[0] += us0.x * a.x + us0.y * a.y
                     + us1.x * b.x + us1.y * b.y;
        }
        #pragma unroll
        for (int n = 0; n < NNEG; ++n) {
            const float2 a = W2[(size_t)n0[n] * (EMBED_D / 2) + lane];
            const float2 b = W2[(size_t)n1[n] * (EMBED_D / 2) + lane];
            accs[1 + n] += us0.x * a.x + us0.y * a.y
                         + us1.x * b.x + us1.y * b.y;
        }
    }

    // ---- wave reduction of the 6 accumulators ----
    #pragma unroll
    for (int k = 0; k < 6; ++k) {
        float v = accs[k];
        #pragma unroll
        for (int off = 32; off > 0; off >>= 1)
            v += __shfl_down(v, off, 64);
        accs[k] = v;
    }

    __shared__ float sred[WPB][6];
    if (lane == 0) {
        #pragma unroll
        for (int k = 0; k < 6; ++k) sred[wib][k] = accs[k];
    }
    __syncthreads();

    if (threadIdx.x < 6) {
        float s = 0.f;
        #pragma unroll
        for (int w = 0; w < WPB; ++w) s += sred[w][threadIdx.x];
        partials[threadIdx.x * NBLOCKS + blockIdx.x] = s;   // [k][block]
    }

    // ---- ticket: last block to finish does the final reduction ----
    __shared__ unsigned int ticket;
    __syncthreads();                         // drains the 6 partial stores (vmcnt) per thread
    if (threadIdx.x == 0) {
        __threadfence();                     // release: make partials visible device-wide (cross-XCD)
        ticket = atomicAdd(counter, 1u);
    }
    __syncthreads();

    if (ticket == NBLOCKS - 1) {
        __threadfence();                     // acquire: invalidate local caches before reading others' partials

        __shared__ float sv[6];
        for (int k = wib; k < 6; k += WPB) { // waves 0..3 take k={0,4},{1,5},{2},{3}
            float s = 0.f;
            for (int i = lane; i < NBLOCKS; i += 64)
                s += partials[k * NBLOCKS + i];
            #pragma unroll
            for (int off = 32; off > 0; off >>= 1)
                s += __shfl_down(s, off, 64);
            if (lane == 0) sv[k] = s;
        }
        __syncthreads();

        if (threadIdx.x == 0) {
            // log_sigmoid(x) = min(x,0) - log1p(exp(-|x|))
            const float spos = sv[0];
            float loss = -(fminf(spos, 0.f) - log1pf(expf(-fabsf(spos))));
            #pragma unroll
            for (int k = 1; k < 6; ++k) {
                const float x = -sv[k];      // log_sigmoid(-s_neg)
                loss -= (fminf(x, 0.f) - log1pf(expf(-fabsf(x))));
            }
            out[0] = loss;
        }
    }
}

extern "C" void kernel_launch(void* const* d_in, const int* in_sizes, int n_in,
                              void* d_out, int out_size, void* d_ws, size_t ws_size,
                              hipStream_t stream) {
    const int*   pos_u = (const int*)d_in[0];
    const int*   pos_w = (const int*)d_in[1];
    const int*   neg_w = (const int*)d_in[2];
    const float* W     = (const float*)d_in[3];
    float* out = (float*)d_out;

    float* partials = (float*)d_ws;                       // 6*NBLOCKS floats = 24 KB
    unsigned int* counter = (unsigned int*)((char*)d_ws + 6 * NBLOCKS * sizeof(float));

    hipMemsetAsync(counter, 0, sizeof(unsigned int), stream);  // capture-safe
    cbow_fused_kernel<<<NBLOCKS, TPB, 0, stream>>>(pos_u, pos_w, neg_w, W,
                                                   partials, counter, out);
}

// Round 5
// 34.746 us; speedup vs baseline: 2.0033x; 2.0033x over previous
//
#include <hip/hip_runtime.h>
#include <math.h>

// Problem constants (match reference)
#define VOCAB   100000
#define EMBED_D 128
#define BATCH_N 16384
#define CTX     8
#define NNEG    5

#define NBLOCKS 2048
#define TPB     256                     // 4 waves/block
#define WPB     (TPB / 64)
#define NWAVES  (NBLOCKS * WPB)         // 8192 waves
#define EPW     (BATCH_N / NWAVES)      // 2 elements per wave (blocked)

// Stage 1: per-block partials of the 6 scalar contractions.
// Wave g owns elements [g*2, g*2+2). Lane i owns dims [2i, 2i+1] (float2);
// a wave gather = one contiguous 512 B row. All index loads are wave-uniform
// (readfirstlane base) -> scalar s_loads. The 12 target-row gathers are
// issued BEFORE the 16 context gathers so they hide under the context-sum
// accumulation: all 28 row loads are in flight per wave at once.
__global__ __launch_bounds__(TPB) void cbow_partial_kernel(
    const int* __restrict__ pos_u,   // [B, C]
    const int* __restrict__ pos_w,   // [B]
    const int* __restrict__ neg_w,   // [B, NEG]
    const float* __restrict__ W,     // [VOCAB, D]
    float* __restrict__ partials)    // [6][NBLOCKS]
{
    const int lane = threadIdx.x & 63;
    const int wib  = threadIdx.x >> 6;
    const int g    = blockIdx.x * WPB + wib;

    const float2* __restrict__ W2 = (const float2*)W;   // 64 float2 per row

    const int e0 = __builtin_amdgcn_readfirstlane(g * EPW);
    const int e1 = e0 + 1;

    // ---- wave-uniform index loads (contiguous -> wide s_loads) ----
    int c0[CTX], c1[CTX];
    #pragma unroll
    for (int c = 0; c < CTX; ++c) {
        c0[c] = pos_u[e0 * CTX + c];
        c1[c] = pos_u[e1 * CTX + c];
    }
    const int ip0 = pos_w[e0];
    const int ip1 = pos_w[e1];
    int n0[NNEG], n1[NNEG];
    #pragma unroll
    for (int n = 0; n < NNEG; ++n) {
        n0[n] = neg_w[e0 * NNEG + n];
        n1[n] = neg_w[e1 * NNEG + n];
    }

    // ---- issue the 12 independent target-row gathers FIRST ----
    const float2 wp0 = W2[(size_t)ip0 * (EMBED_D / 2) + lane];
    const float2 wp1 = W2[(size_t)ip1 * (EMBED_D / 2) + lane];
    float2 t0[NNEG], t1[NNEG];
    #pragma unroll
    for (int n = 0; n < NNEG; ++n) {
        t0[n] = W2[(size_t)n0[n] * (EMBED_D / 2) + lane];
        t1[n] = W2[(size_t)n1[n] * (EMBED_D / 2) + lane];
    }

    // ---- 16 context gathers + context-sum accumulation ----
    float2 us0 = make_float2(0.f, 0.f);
    float2 us1 = make_float2(0.f, 0.f);
    #pragma unroll
    for (int c = 0; c < CTX; ++c) {
        const float2 a = W2[(size_t)c0[c] * (EMBED_D / 2) + lane];
        const float2 b = W2[(size_t)c1[c] * (EMBED_D / 2) + lane];
        us0.x += a.x; us0.y += a.y;
        us1.x += b.x; us1.y += b.y;
    }

    // ---- dot partials ----
    float accs[6];
    accs[0] = us0.x * wp0.x + us0.y * wp0.y
            + us1.x * wp1.x + us1.y * wp1.y;
    #pragma unroll
    for (int n = 0; n < NNEG; ++n) {
        accs[1 + n] = us0.x * t0[n].x + us0.y * t0[n].y
                    + us1.x * t1[n].x + us1.y * t1[n].y;
    }

    // ---- wave reduction of the 6 accumulators ----
    #pragma unroll
    for (int k = 0; k < 6; ++k) {
        float v = accs[k];
        #pragma unroll
        for (int off = 32; off > 0; off >>= 1)
            v += __shfl_down(v, off, 64);
        accs[k] = v;
    }

    __shared__ float sred[WPB][6];
    if (lane == 0) {
        #pragma unroll
        for (int k = 0; k < 6; ++k) sred[wib][k] = accs[k];
    }
    __syncthreads();

    if (threadIdx.x < 6) {
        float s = 0.f;
        #pragma unroll
        for (int w = 0; w < WPB; ++w) s += sred[w][threadIdx.x];
        partials[threadIdx.x * NBLOCKS + blockIdx.x] = s;   // [k][block]
    }
}

// Stage 2: 6 waves; wave k reduces partials[k][*] coalesced; thread 0 epilogue.
__global__ __launch_bounds__(384) void cbow_final_kernel(
    const float* __restrict__ partials, float* __restrict__ out)
{
    const int wave = threadIdx.x >> 6;   // 0..5 -> k
    const int lane = threadIdx.x & 63;

    float s = 0.f;
    for (int i = lane; i < NBLOCKS; i += 64)
        s += partials[wave * NBLOCKS + i];
    #pragma unroll
    for (int off = 32; off > 0; off >>= 1)
        s += __shfl_down(s, off, 64);

    __shared__ float sv[6];
    if (lane == 0) sv[wave] = s;
    __syncthreads();

    if (threadIdx.x == 0) {
        // log_sigmoid(x) = min(x,0) - log1p(exp(-|x|))
        const float spos = sv[0];
        float loss = -(fminf(spos, 0.f) - log1pf(expf(-fabsf(spos))));
        #pragma unroll
        for (int k = 1; k < 6; ++k) {
            const float x = -sv[k];      // log_sigmoid(-s_neg)
            loss -= (fminf(x, 0.f) - log1pf(expf(-fabsf(x))));
        }
        out[0] = loss;
    }
}

extern "C" void kernel_launch(void* const* d_in, const int* in_sizes, int n_in,
                              void* d_out, int out_size, void* d_ws, size_t ws_size,
                              hipStream_t stream) {
    const int*   pos_u = (const int*)d_in[0];
    const int*   pos_w = (const int*)d_in[1];
    const int*   neg_w = (const int*)d_in[2];
    const float* W     = (const float*)d_in[3];
    float* out = (float*)d_out;
    float* partials = (float*)d_ws;   // 6*NBLOCKS floats = 48 KB

    cbow_partial_kernel<<<NBLOCKS, TPB, 0, stream>>>(pos_u, pos_w, neg_w, W, partials);
    cbow_final_kernel<<<1, 384, 0, stream>>>(partials, out);
}